// Round 3
// baseline (785.094 us; speedup 1.0000x reference)
//
#include <hip/hip_runtime.h>
#include <hip/hip_bf16.h>
#include <stdint.h>

// CapsuleLayer dynamic routing v3.
// b_r[b,j,i] = sum_k u_hat[b,j,i,k] * Vacc[b,j,k]  (Vacc = sum of prior v's)
// Layout C: lane = (j:0-31 | kh bit5); thread owns 1 j, 8 k's, 4 batches in
// registers. W_i staged to LDS via registers (coalesced), XOR-swizzled rows.

#define B_TOT   128
#define J_CAPS  32
#define I_CAPS  1152
#define K_DIM   16
#define L_DIM   8

#define I_TILE  12
#define NSLICE  (I_CAPS / I_TILE)     // 96 -> grid 8*96 = 768 = 3 WG/CU
#define NBG     8                     // batch groups (16 b per WG)
#define WJ      (I_CAPS * 128)        // floats between j planes

template<int R>
__global__ __launch_bounds__(256, 3)
void caps_route(const float* __restrict__ x,     // [128,1152,8]
                const float* __restrict__ W,     // [32,1152,16,8]
                const float* __restrict__ Vacc,  // [128,32,16]
                float* __restrict__ s)           // [128,32,16] zeroed
{
    __shared__ float Wt[2][4096];     // 2 x 16KB W_i tiles, swizzled rows

    const int tid  = threadIdx.x;
    const int lane = tid & 63;
    const int wv   = tid >> 6;        // wave 0..3
    const int j    = lane & 31;
    const int kh   = lane >> 5;       // k half (0: k0-7, 1: k8-15)
    const int bg   = blockIdx.x / NSLICE;
    const int sl   = blockIdx.x % NSLICE;
    const int i0   = sl * I_TILE;
    const int b0   = bg * 16 + wv * 4;   // this wave's 4 batches

    // ---- staging geometry: thread covers 16B granules {tid + 256u} ----
    // granule g -> tile floats [4g,4g+3]; j_s = g/32 = tid/32 + 8u;
    // c = (g%32)*4 (const across u). LDS row r = (c>>6)*32 + j_s.
    const int cg  = tid & 31;
    const int c   = cg * 4;              // float col within j-plane (0..124)
    const int khs = c >> 6;              // which k-half
    const int cb  = (c & 63) * 4;        // byte col within 256B row
    const int jsb = tid >> 5;            // j_s base (0..7), +8 per chunk

    int wofs[4];
    const float* wsrc[4];
    #pragma unroll
    for (int u = 0; u < 4; ++u) {
        const int js = jsb + 8 * u;
        const int r  = khs * 32 + js;
        wofs[u] = r * 256 + (cb ^ ((r & 7) << 4));
        wsrc[u] = W + (size_t)js * WJ + c;
    }

    float4 st[4];
    #pragma unroll
    for (int u = 0; u < 4; ++u)
        st[u] = *reinterpret_cast<const float4*>(wsrc[u] + (size_t)i0 * 128);

    // Vacc fragment (prescaled to log2 domain)
    float Vr[4][8];
    if (R > 0) {
        #pragma unroll
        for (int bb = 0; bb < 4; ++bb) {
            const float4 va = *reinterpret_cast<const float4*>(
                Vacc + ((size_t)(b0 + bb) * J_CAPS + j) * K_DIM + kh * 8);
            const float4 vb = *reinterpret_cast<const float4*>(
                Vacc + ((size_t)(b0 + bb) * J_CAPS + j) * K_DIM + kh * 8 + 4);
            Vr[bb][0] = va.x * 1.44269504f; Vr[bb][1] = va.y * 1.44269504f;
            Vr[bb][2] = va.z * 1.44269504f; Vr[bb][3] = va.w * 1.44269504f;
            Vr[bb][4] = vb.x * 1.44269504f; Vr[bb][5] = vb.y * 1.44269504f;
            Vr[bb][6] = vb.z * 1.44269504f; Vr[bb][7] = vb.w * 1.44269504f;
        }
    }

    float sacc[4][8];
    #pragma unroll
    for (int bb = 0; bb < 4; ++bb)
        #pragma unroll
        for (int kk = 0; kk < 8; ++kk) sacc[bb][kk] = 0.0f;

    // write first tile
    {
        char* lb = reinterpret_cast<char*>(&Wt[0][0]);
        #pragma unroll
        for (int u = 0; u < 4; ++u)
            *reinterpret_cast<float4*>(lb + wofs[u]) = st[u];
    }
    __syncthreads();

    const int sw = (j & 7) << 4;     // read-side swizzle (row = lane)

    for (int ii = 0; ii < I_TILE; ++ii) {
        const int cur = ii & 1;
        const int i   = i0 + ii;

        if (ii + 1 < I_TILE) {
            #pragma unroll
            for (int u = 0; u < 4; ++u)
                st[u] = *reinterpret_cast<const float4*>(
                    wsrc[u] + (size_t)(i + 1) * 128);
        }

        // x broadcast loads (same addr across lanes -> 1 line each)
        float4 xa[4], xb[4];
        #pragma unroll
        for (int bb = 0; bb < 4; ++bb) {
            const float* xp = x + ((size_t)(b0 + bb) * I_CAPS + i) * L_DIM;
            xa[bb] = *reinterpret_cast<const float4*>(xp);
            xb[bb] = *reinterpret_cast<const float4*>(xp + 4);
        }

        const char* lbase =
            reinterpret_cast<const char*>(&Wt[cur][0]) + lane * 256;

        float u[4][8];
        #pragma unroll
        for (int kk = 0; kk < 8; ++kk) {
            const float4 w0 = *reinterpret_cast<const float4*>(
                lbase + ((kk * 32 +  0) ^ sw));
            const float4 w1 = *reinterpret_cast<const float4*>(
                lbase + ((kk * 32 + 16) ^ sw));
            #pragma unroll
            for (int bb = 0; bb < 4; ++bb) {
                float acc;
                acc = w0.x * xa[bb].x;
                acc = fmaf(w0.y, xa[bb].y, acc);
                acc = fmaf(w0.z, xa[bb].z, acc);
                acc = fmaf(w0.w, xa[bb].w, acc);
                acc = fmaf(w1.x, xb[bb].x, acc);
                acc = fmaf(w1.y, xb[bb].y, acc);
                acc = fmaf(w1.z, xb[bb].z, acc);
                acc = fmaf(w1.w, xb[bb].w, acc);
                u[bb][kk] = acc;
            }
        }

        if (R == 0) {
            #pragma unroll
            for (int bb = 0; bb < 4; ++bb)
                #pragma unroll
                for (int kk = 0; kk < 8; ++kk)
                    sacc[bb][kk] = fmaf(0.03125f, u[bb][kk], sacc[bb][kk]);
        } else {
            #pragma unroll
            for (int bb = 0; bb < 4; ++bb) {
                float p = u[bb][0] * Vr[bb][0];
                #pragma unroll
                for (int kk = 1; kk < 8; ++kk)
                    p = fmaf(u[bb][kk], Vr[bb][kk], p);
                p += __shfl_xor(p, 32);          // add other k-half
                // max over 32 j (lanes 0-4 bits)
                float m = p;
                m = fmaxf(m, __shfl_xor(m, 1));
                m = fmaxf(m, __shfl_xor(m, 2));
                m = fmaxf(m, __shfl_xor(m, 4));
                m = fmaxf(m, __shfl_xor(m, 8));
                m = fmaxf(m, __shfl_xor(m, 16));
                const float e = exp2f(p - m);
                float den = e;
                den += __shfl_xor(den, 1);
                den += __shfl_xor(den, 2);
                den += __shfl_xor(den, 4);
                den += __shfl_xor(den, 8);
                den += __shfl_xor(den, 16);
                const float cfac = e * __builtin_amdgcn_rcpf(den);
                #pragma unroll
                for (int kk = 0; kk < 8; ++kk)
                    sacc[bb][kk] = fmaf(cfac, u[bb][kk], sacc[bb][kk]);
            }
        }

        if (ii + 1 < I_TILE) {
            char* lb = reinterpret_cast<char*>(&Wt[cur ^ 1][0]);
            #pragma unroll
            for (int u = 0; u < 4; ++u)
                *reinterpret_cast<float4*>(lb + wofs[u]) = st[u];
        }
        __syncthreads();
    }

    #pragma unroll
    for (int bb = 0; bb < 4; ++bb)
        #pragma unroll
        for (int kk = 0; kk < 8; ++kk)
            atomicAdd(&s[((size_t)(b0 + bb) * J_CAPS + j) * K_DIM + kh * 8 + kk],
                      sacc[bb][kk]);
}

// MODE 0: Vacc = v, zero s;  MODE 1: Vacc += v, zero s;  MODE 2: out = v
template<int MODE>
__global__ __launch_bounds__(256)
void caps_squash(float* __restrict__ s,
                 float* __restrict__ Vacc,
                 float* __restrict__ out)
{
    const int t = blockIdx.x * 256 + threadIdx.x;   // (b,j,k), k fastest
    const float sv = s[t];
    float p = sv * sv;
    p += __shfl_xor(p, 1);
    p += __shfl_xor(p, 2);
    p += __shfl_xor(p, 4);
    p += __shfl_xor(p, 8);
    const float scale = p / ((1.0f + p) * sqrtf(p + 1e-7f));
    const float v = scale * sv;
    if (MODE == 0)      { Vacc[t] = v;  s[t] = 0.0f; }
    else if (MODE == 1) { Vacc[t] += v; s[t] = 0.0f; }
    else                { out[t] = v; }
}

extern "C" void kernel_launch(void* const* d_in, const int* in_sizes, int n_in,
                              void* d_out, int out_size, void* d_ws, size_t ws_size,
                              hipStream_t stream)
{
    const float* x = (const float*)d_in[0];   // [128,1152,8]
    const float* W = (const float*)d_in[1];   // [32,1152,16,8]
    float* out  = (float*)d_out;              // [128,32,16]
    float* Vacc = (float*)d_ws;               // 65536 floats
    float* s    = Vacc + 65536;               // 65536 floats

    hipMemsetAsync(s, 0, (size_t)65536 * sizeof(float), stream);

    dim3 grid(NBG * NSLICE);   // 768 WGs
    dim3 blk(256);

    caps_route<0><<<grid, blk, 0, stream>>>(x, W, Vacc, s);
    caps_squash<0><<<256, 256, 0, stream>>>(s, Vacc, out);

    caps_route<1><<<grid, blk, 0, stream>>>(x, W, Vacc, s);
    caps_squash<1><<<256, 256, 0, stream>>>(s, Vacc, out);

    caps_route<2><<<grid, blk, 0, stream>>>(x, W, Vacc, s);
    caps_squash<2><<<256, 256, 0, stream>>>(s, Vacc, out);
}

// Round 4
// 581.535 us; speedup vs baseline: 1.3500x; 1.3500x over previous
//
#include <hip/hip_runtime.h>
#include <hip/hip_bf16.h>
#include <stdint.h>

// CapsuleLayer dynamic routing v4.
// b_r[b,j,i] = sum_k u_hat[b,j,i,k] * Vacc[b,j,k]  (Vacc = sum of prior v's)
// Layout: lane=(j | kh<<5); thread owns 1 j, 8 k's, 4 batches.
// W_i tile (16KB) staged via global_load_lds with PRE-SWIZZLED source
// (LDS dest linear, swizzle byte^=(row&15)<<4 carried by the source address),
// double-buffered. Occupancy pinned with amdgpu_waves_per_eu(2,2) so the
// register allocator does NOT spill (v2/v3 regression: 84-VGPR target +
// ~1KB/thread scratch traffic, WRITE_SIZE 211MB).

#define B_TOT   128
#define J_CAPS  32
#define I_CAPS  1152
#define K_DIM   16
#define L_DIM   8

#define I_TILE  18
#define NSLICE  (I_CAPS / I_TILE)     // 64 -> grid 8*64 = 512 = 2 WG/CU exact
#define WJ      (I_CAPS * 128)        // floats between j planes

template<int R>
__global__ __launch_bounds__(256)
__attribute__((amdgpu_waves_per_eu(2, 2)))
void caps_route(const float* __restrict__ x,     // [128,1152,8]
                const float* __restrict__ W,     // [32,1152,16,8]
                const float* __restrict__ Vacc,  // [128,32,16]
                float* __restrict__ s)           // [128,32,16] zeroed
{
    __shared__ float Wt[2][4096];     // 2 x 16KB W_i tiles
    __shared__ float xs[16 * 144];    // [bl][18*8] x slice, 9KB

    const int tid  = threadIdx.x;
    const int lane = tid & 63;
    const int wv   = tid >> 6;        // wave 0..3
    const int j    = lane & 31;
    const int kh   = lane >> 5;       // k half
    const int bg   = blockIdx.x / NSLICE;
    const int sl   = blockIdx.x % NSLICE;
    const int i0   = sl * I_TILE;
    const int b0   = bg * 16 + wv * 4;

    // ---- pre-swizzled global sources for global_load_lds ----
    // LDS byte q = (wv*4+t)*1024 + lane*16 (linear dest). Inverse swizzle:
    // row rr=q>>8, cb=(q&255)^((rr&15)<<4); js=rr&31; c=(rr>>5)*64+cb/4.
    const float* wsrc[4];
    #pragma unroll
    for (int t = 0; t < 4; ++t) {
        const int q  = (wv * 4 + t) * 1024 + lane * 16;
        const int rr = q >> 8;
        const int cb = (q & 255) ^ ((rr & 15) << 4);
        const int js = rr & 31;
        const int c  = (rr >> 5) * 64 + (cb >> 2);
        wsrc[t] = W + (size_t)js * WJ + c;
    }

    auto stage = [&](int buf, int i) {
        #pragma unroll
        for (int t = 0; t < 4; ++t)
            __builtin_amdgcn_global_load_lds(
                (const __attribute__((address_space(1))) uint32_t*)
                    (wsrc[t] + (size_t)i * 128),
                (__attribute__((address_space(3))) uint32_t*)
                    &Wt[buf][(wv * 4 + t) * 256],
                16, 0, 0);
    };

    stage(0, i0);

    // ---- x slice -> LDS (576 float4s, coalesced) ----
    for (int cf = tid; cf < 576; cf += 256) {
        const int bl = cf / 36;
        const int rm = cf - bl * 36;
        float4 v = *reinterpret_cast<const float4*>(
            x + ((size_t)(bg * 16 + bl) * I_CAPS + i0) * 8 + rm * 4);
        *reinterpret_cast<float4*>(xs + bl * 144 + rm * 4) = v;
    }

    // Vacc fragment, prescaled to log2 domain
    float Vr[4][8];
    if (R > 0) {
        #pragma unroll
        for (int bb = 0; bb < 4; ++bb) {
            const float* vp =
                Vacc + ((size_t)(b0 + bb) * J_CAPS + j) * K_DIM + kh * 8;
            const float4 va = *reinterpret_cast<const float4*>(vp);
            const float4 vb = *reinterpret_cast<const float4*>(vp + 4);
            Vr[bb][0] = va.x * 1.44269504f; Vr[bb][1] = va.y * 1.44269504f;
            Vr[bb][2] = va.z * 1.44269504f; Vr[bb][3] = va.w * 1.44269504f;
            Vr[bb][4] = vb.x * 1.44269504f; Vr[bb][5] = vb.y * 1.44269504f;
            Vr[bb][6] = vb.z * 1.44269504f; Vr[bb][7] = vb.w * 1.44269504f;
        }
    }

    float sacc[4][8];
    #pragma unroll
    for (int bb = 0; bb < 4; ++bb)
        #pragma unroll
        for (int kk = 0; kk < 8; ++kk) sacc[bb][kk] = 0.0f;

    __syncthreads();   // drains vmcnt: first W tile + xs ready

    const int sw = (j & 15) << 4;    // read-side swizzle (row = lane)

    for (int ii = 0; ii < I_TILE; ++ii) {
        const int cur = ii & 1;
        if (ii + 1 < I_TILE) stage(cur ^ 1, i0 + ii + 1);

        float4 xa[4], xb[4];
        #pragma unroll
        for (int bb = 0; bb < 4; ++bb) {
            const float* xp = xs + (wv * 4 + bb) * 144 + ii * 8;
            xa[bb] = *reinterpret_cast<const float4*>(xp);
            xb[bb] = *reinterpret_cast<const float4*>(xp + 4);
        }

        const char* lbase =
            reinterpret_cast<const char*>(&Wt[cur][0]) + lane * 256;

        float u[4][8];
        #pragma unroll
        for (int kk = 0; kk < 8; ++kk) {
            const float4 w0 = *reinterpret_cast<const float4*>(
                lbase + ((kk * 32) ^ sw));
            const float4 w1 = *reinterpret_cast<const float4*>(
                lbase + ((kk * 32 + 16) ^ sw));
            #pragma unroll
            for (int bb = 0; bb < 4; ++bb) {
                float acc;
                acc = w0.x * xa[bb].x;
                acc = fmaf(w0.y, xa[bb].y, acc);
                acc = fmaf(w0.z, xa[bb].z, acc);
                acc = fmaf(w0.w, xa[bb].w, acc);
                acc = fmaf(w1.x, xb[bb].x, acc);
                acc = fmaf(w1.y, xb[bb].y, acc);
                acc = fmaf(w1.z, xb[bb].z, acc);
                acc = fmaf(w1.w, xb[bb].w, acc);
                u[bb][kk] = acc;
            }
        }

        if (R == 0) {
            #pragma unroll
            for (int bb = 0; bb < 4; ++bb)
                #pragma unroll
                for (int kk = 0; kk < 8; ++kk)
                    sacc[bb][kk] = fmaf(0.03125f, u[bb][kk], sacc[bb][kk]);
        } else {
            #pragma unroll
            for (int bb = 0; bb < 4; ++bb) {
                float p = u[bb][0] * Vr[bb][0];
                #pragma unroll
                for (int kk = 1; kk < 8; ++kk)
                    p = fmaf(u[bb][kk], Vr[bb][kk], p);
                p += __shfl_xor(p, 32);          // add other k-half
                float m = p;                     // max over 32 j's
                m = fmaxf(m, __shfl_xor(m, 1));
                m = fmaxf(m, __shfl_xor(m, 2));
                m = fmaxf(m, __shfl_xor(m, 4));
                m = fmaxf(m, __shfl_xor(m, 8));
                m = fmaxf(m, __shfl_xor(m, 16));
                const float e = exp2f(p - m);
                float den = e;
                den += __shfl_xor(den, 1);
                den += __shfl_xor(den, 2);
                den += __shfl_xor(den, 4);
                den += __shfl_xor(den, 8);
                den += __shfl_xor(den, 16);
                const float cfac = e * __builtin_amdgcn_rcpf(den);
                #pragma unroll
                for (int kk = 0; kk < 8; ++kk)
                    sacc[bb][kk] = fmaf(cfac, u[bb][kk], sacc[bb][kk]);
            }
        }
        __syncthreads();   // prefetch landed (vmcnt0) + reads of cur done
    }

    #pragma unroll
    for (int bb = 0; bb < 4; ++bb)
        #pragma unroll
        for (int kk = 0; kk < 8; ++kk)
            atomicAdd(&s[((size_t)(b0 + bb) * J_CAPS + j) * K_DIM + kh * 8 + kk],
                      sacc[bb][kk]);
}

// MODE 0: Vacc = v, zero s;  MODE 1: Vacc += v, zero s;  MODE 2: out = v
template<int MODE>
__global__ __launch_bounds__(256)
void caps_squash(float* __restrict__ s,
                 float* __restrict__ Vacc,
                 float* __restrict__ out)
{
    const int t = blockIdx.x * 256 + threadIdx.x;   // (b,j,k), k fastest
    const float sv = s[t];
    float p = sv * sv;
    p += __shfl_xor(p, 1);
    p += __shfl_xor(p, 2);
    p += __shfl_xor(p, 4);
    p += __shfl_xor(p, 8);
    const float scale = p / ((1.0f + p) * sqrtf(p + 1e-7f));
    const float v = scale * sv;
    if (MODE == 0)      { Vacc[t] = v;  s[t] = 0.0f; }
    else if (MODE == 1) { Vacc[t] += v; s[t] = 0.0f; }
    else                { out[t] = v; }
}

extern "C" void kernel_launch(void* const* d_in, const int* in_sizes, int n_in,
                              void* d_out, int out_size, void* d_ws, size_t ws_size,
                              hipStream_t stream)
{
    const float* x = (const float*)d_in[0];   // [128,1152,8]
    const float* W = (const float*)d_in[1];   // [32,1152,16,8]
    float* out  = (float*)d_out;              // [128,32,16]
    float* Vacc = (float*)d_ws;               // 65536 floats
    float* s    = Vacc + 65536;               // 65536 floats

    hipMemsetAsync(s, 0, (size_t)65536 * sizeof(float), stream);

    dim3 grid(8 * NSLICE);   // 512 WGs = 2/CU exact
    dim3 blk(256);

    caps_route<0><<<grid, blk, 0, stream>>>(x, W, Vacc, s);
    caps_squash<0><<<256, 256, 0, stream>>>(s, Vacc, out);

    caps_route<1><<<grid, blk, 0, stream>>>(x, W, Vacc, s);
    caps_squash<1><<<256, 256, 0, stream>>>(s, Vacc, out);

    caps_route<2><<<grid, blk, 0, stream>>>(x, W, Vacc, s);
    caps_squash<2><<<256, 256, 0, stream>>>(s, Vacc, out);
}

// Round 5
// 379.186 us; speedup vs baseline: 2.0705x; 1.5336x over previous
//
#include <hip/hip_runtime.h>
#include <hip/hip_bf16.h>
#include <stdint.h>

// CapsuleLayer dynamic routing v5.
// b_r[b,j,i] = sum_k u_hat[b,j,i,k] * Vacc[b,j,k]  (Vacc = sum of prior v's)
// Lane = (j:0-31 | kh bit5). Thread owns 1 j, 8 k's, NB=2 batches (register
// demand ~100 -> no scratch spill; v2-v4 all spilled, WRITE_SIZE 99-211MB).
// Paired softmax: kh=0 lanes reduce batch 0, kh=1 lanes batch 1, one
// shfl_xor(32) swap at the end; no max-subtract (|logit| small, fp32 safe).
// W_i tile (16KB) via global_load_lds, pre-swizzled source, double-buffered
// (v4-proven: FETCH 12.8MB, bank conflicts 0).

#define B_TOT   128
#define J_CAPS  32
#define I_CAPS  1152
#define K_DIM   16
#define L_DIM   8

#define I_TILE  24
#define NSLICE  (I_CAPS / I_TILE)     // 48 -> grid 16*48 = 768 = 3 WG/CU
#define WJ      (I_CAPS * 128)        // floats between j planes

template<int R>
__global__ __launch_bounds__(256)
__attribute__((amdgpu_waves_per_eu(3, 3)))
void caps_route(const float* __restrict__ x,     // [128,1152,8]
                const float* __restrict__ W,     // [32,1152,16,8]
                const float* __restrict__ Vacc,  // [128,32,16]
                float* __restrict__ s)           // [128,32,16] zeroed
{
    __shared__ float Wt[2][4096];     // 2 x 16KB W_i tiles
    __shared__ float xs[8 * 192];     // [bl][24*8], 6KB

    const int tid  = threadIdx.x;
    const int lane = tid & 63;
    const int wv   = tid >> 6;        // wave 0..3
    const int j    = lane & 31;
    const int kh   = lane >> 5;       // k half
    const int bg   = blockIdx.x / NSLICE;   // 0..15
    const int sl   = blockIdx.x % NSLICE;   // 0..47
    const int i0   = sl * I_TILE;
    const int b0   = bg * 8 + wv * 2;       // this wave's 2 batches

    // ---- pre-swizzled global sources for global_load_lds (v4-proven) ----
    // LDS byte q = (wv*4+t)*1024 + lane*16 (linear dest). Inverse swizzle:
    // row rr=q>>8, cb=(q&255)^((rr&15)<<4); js=rr&31; c=(rr>>5)*64+cb/4.
    const float* wsrc[4];
    #pragma unroll
    for (int t = 0; t < 4; ++t) {
        const int q  = (wv * 4 + t) * 1024 + lane * 16;
        const int rr = q >> 8;
        const int cb = (q & 255) ^ ((rr & 15) << 4);
        const int js = rr & 31;
        const int c  = (rr >> 5) * 64 + (cb >> 2);
        wsrc[t] = W + (size_t)js * WJ + c;
    }

    auto stage = [&](int buf, int i) {
        #pragma unroll
        for (int t = 0; t < 4; ++t)
            __builtin_amdgcn_global_load_lds(
                (const __attribute__((address_space(1))) uint32_t*)
                    (wsrc[t] + (size_t)i * 128),
                (__attribute__((address_space(3))) uint32_t*)
                    &Wt[buf][(wv * 4 + t) * 256],
                16, 0, 0);
    };

    stage(0, i0);

    // ---- x slice -> LDS (384 float4s, coalesced) ----
    for (int cf = tid; cf < 384; cf += 256) {
        const int bl = cf / 48;
        const int rm = cf - bl * 48;
        float4 v = *reinterpret_cast<const float4*>(
            x + ((size_t)(bg * 8 + bl) * I_CAPS + i0) * 8 + rm * 4);
        *reinterpret_cast<float4*>(xs + bl * 192 + rm * 4) = v;
    }

    // Vacc fragment, prescaled to log2 domain
    float Vr[2][8];
    if (R > 0) {
        #pragma unroll
        for (int bb = 0; bb < 2; ++bb) {
            const float* vp =
                Vacc + ((size_t)(b0 + bb) * J_CAPS + j) * K_DIM + kh * 8;
            const float4 va = *reinterpret_cast<const float4*>(vp);
            const float4 vb = *reinterpret_cast<const float4*>(vp + 4);
            Vr[bb][0] = va.x * 1.44269504f; Vr[bb][1] = va.y * 1.44269504f;
            Vr[bb][2] = va.z * 1.44269504f; Vr[bb][3] = va.w * 1.44269504f;
            Vr[bb][4] = vb.x * 1.44269504f; Vr[bb][5] = vb.y * 1.44269504f;
            Vr[bb][6] = vb.z * 1.44269504f; Vr[bb][7] = vb.w * 1.44269504f;
        }
    }

    float sacc[2][8];
    #pragma unroll
    for (int bb = 0; bb < 2; ++bb)
        #pragma unroll
        for (int kk = 0; kk < 8; ++kk) sacc[bb][kk] = 0.0f;

    __syncthreads();   // drains vmcnt: first W tile + xs ready

    const int sw = (j & 15) << 4;    // read-side swizzle (row = lane)

    for (int ii = 0; ii < I_TILE; ++ii) {
        const int cur = ii & 1;
        if (ii + 1 < I_TILE) stage(cur ^ 1, i0 + ii + 1);

        // x fragments: wave-uniform LDS address -> broadcast, conflict-free
        float4 xa[2], xb[2];
        #pragma unroll
        for (int bb = 0; bb < 2; ++bb) {
            const float* xp = xs + (wv * 2 + bb) * 192 + ii * 8;
            xa[bb] = *reinterpret_cast<const float4*>(xp);
            xb[bb] = *reinterpret_cast<const float4*>(xp + 4);
        }

        const char* lbase =
            reinterpret_cast<const char*>(&Wt[cur][0]) + lane * 256;

        float u[2][8];
        #pragma unroll
        for (int kk = 0; kk < 8; ++kk) {
            const float4 w0 = *reinterpret_cast<const float4*>(
                lbase + ((kk * 32) ^ sw));
            const float4 w1 = *reinterpret_cast<const float4*>(
                lbase + ((kk * 32 + 16) ^ sw));
            #pragma unroll
            for (int bb = 0; bb < 2; ++bb) {
                float acc;
                acc = w0.x * xa[bb].x;
                acc = fmaf(w0.y, xa[bb].y, acc);
                acc = fmaf(w0.z, xa[bb].z, acc);
                acc = fmaf(w0.w, xa[bb].w, acc);
                acc = fmaf(w1.x, xb[bb].x, acc);
                acc = fmaf(w1.y, xb[bb].y, acc);
                acc = fmaf(w1.z, xb[bb].z, acc);
                acc = fmaf(w1.w, xb[bb].w, acc);
                u[bb][kk] = acc;
            }
        }

        if (R == 0) {
            #pragma unroll
            for (int bb = 0; bb < 2; ++bb)
                #pragma unroll
                for (int kk = 0; kk < 8; ++kk)
                    sacc[bb][kk] = fmaf(0.03125f, u[bb][kk], sacc[bb][kk]);
        } else {
            // logits (log2 domain), full-k via one cross-half shuffle each
            float p0 = u[0][0] * Vr[0][0];
            float p1 = u[1][0] * Vr[1][0];
            #pragma unroll
            for (int kk = 1; kk < 8; ++kk) {
                p0 = fmaf(u[0][kk], Vr[0][kk], p0);
                p1 = fmaf(u[1][kk], Vr[1][kk], p1);
            }
            p0 += __shfl_xor(p0, 32);
            p1 += __shfl_xor(p1, 32);
            // paired softmax: kh=0 half handles batch 0, kh=1 half batch 1
            const float pq = kh ? p1 : p0;
            const float e  = exp2f(pq);          // no max-subtract: |pq| small
            float den = e;
            den += __shfl_xor(den, 1);
            den += __shfl_xor(den, 2);
            den += __shfl_xor(den, 4);
            den += __shfl_xor(den, 8);
            den += __shfl_xor(den, 16);
            const float cf_own = e * __builtin_amdgcn_rcpf(den);
            const float cf_oth = __shfl_xor(cf_own, 32);
            const float cf0 = kh ? cf_oth : cf_own;
            const float cf1 = kh ? cf_own : cf_oth;
            #pragma unroll
            for (int kk = 0; kk < 8; ++kk) {
                sacc[0][kk] = fmaf(cf0, u[0][kk], sacc[0][kk]);
                sacc[1][kk] = fmaf(cf1, u[1][kk], sacc[1][kk]);
            }
        }
        __syncthreads();   // prefetch landed (vmcnt0) + reads of cur done
    }

    #pragma unroll
    for (int bb = 0; bb < 2; ++bb)
        #pragma unroll
        for (int kk = 0; kk < 8; ++kk)
            atomicAdd(&s[((size_t)(b0 + bb) * J_CAPS + j) * K_DIM + kh * 8 + kk],
                      sacc[bb][kk]);
}

// MODE 0: Vacc = v, zero s;  MODE 1: Vacc += v, zero s;  MODE 2: out = v
template<int MODE>
__global__ __launch_bounds__(256)
void caps_squash(float* __restrict__ s,
                 float* __restrict__ Vacc,
                 float* __restrict__ out)
{
    const int t = blockIdx.x * 256 + threadIdx.x;   // (b,j,k), k fastest
    const float sv = s[t];
    float p = sv * sv;
    p += __shfl_xor(p, 1);
    p += __shfl_xor(p, 2);
    p += __shfl_xor(p, 4);
    p += __shfl_xor(p, 8);
    const float scale = p / ((1.0f + p) * sqrtf(p + 1e-7f));
    const float v = scale * sv;
    if (MODE == 0)      { Vacc[t] = v;  s[t] = 0.0f; }
    else if (MODE == 1) { Vacc[t] += v; s[t] = 0.0f; }
    else                { out[t] = v; }
}

extern "C" void kernel_launch(void* const* d_in, const int* in_sizes, int n_in,
                              void* d_out, int out_size, void* d_ws, size_t ws_size,
                              hipStream_t stream)
{
    const float* x = (const float*)d_in[0];   // [128,1152,8]
    const float* W = (const float*)d_in[1];   // [32,1152,16,8]
    float* out  = (float*)d_out;              // [128,32,16]
    float* Vacc = (float*)d_ws;               // 65536 floats
    float* s    = Vacc + 65536;               // 65536 floats

    hipMemsetAsync(s, 0, (size_t)65536 * sizeof(float), stream);

    dim3 grid(16 * NSLICE);   // 768 WGs = 3/CU
    dim3 blk(256);

    caps_route<0><<<grid, blk, 0, stream>>>(x, W, Vacc, s);
    caps_squash<0><<<256, 256, 0, stream>>>(s, Vacc, out);

    caps_route<1><<<grid, blk, 0, stream>>>(x, W, Vacc, s);
    caps_squash<1><<<256, 256, 0, stream>>>(s, Vacc, out);

    caps_route<2><<<grid, blk, 0, stream>>>(x, W, Vacc, s);
    caps_squash<2><<<256, 256, 0, stream>>>(s, Vacc, out);
}

// Round 6
// 133.790 us; speedup vs baseline: 5.8681x; 2.8342x over previous
//
#include <hip/hip_runtime.h>
#include <hip/hip_bf16.h>
#include <stdint.h>

// CapsuleLayer dynamic routing v6.
// b_r[b,j,i] = sum_k u_hat[b,j,i,k] * Vacc[b,j,k]  (Vacc = sum of prior v's)
// Lane = (j:0-31 | kh bit5). Thread owns 1 j, 8 k's, NB=2 batches.
// W_i tile (16KB) via global_load_lds, pre-swizzled source, double-buffered
// (v4/v5-proven: FETCH ~13MB, bank conflicts 0).
// v6 FIX: epilogue atomics were 64-lane-scattered (64 lines/instr) -> L2
// wrote back ~32B per lane-atomic = ~100MB/dispatch (v2-v5 were write-bound
// on this). Now: per-wave LDS transpose (reusing dead Wt), then atomics on
// 64 CONTIGUOUS addresses per instruction (4 lines) -> ~16KB/WG writeback.

#define B_TOT   128
#define J_CAPS  32
#define I_CAPS  1152
#define K_DIM   16
#define L_DIM   8

#define I_TILE  24
#define NSLICE  (I_CAPS / I_TILE)     // 48 -> grid 16*48 = 768 = 3 WG/CU
#define WJ      (I_CAPS * 128)        // floats between j planes

template<int R>
__global__ __launch_bounds__(256)
void caps_route(const float* __restrict__ x,     // [128,1152,8]
                const float* __restrict__ W,     // [32,1152,16,8]
                const float* __restrict__ Vacc,  // [128,32,16]
                float* __restrict__ s)           // [128,32,16] zeroed
{
    __shared__ float Wt[2][4096];     // 2 x 16KB W_i tiles; dead after loop
    __shared__ float xs[8 * 192];     // [bl][24*8], 6KB

    const int tid  = threadIdx.x;
    const int lane = tid & 63;
    const int wv   = tid >> 6;        // wave 0..3
    const int j    = lane & 31;
    const int kh   = lane >> 5;       // k half
    const int bg   = blockIdx.x / NSLICE;   // 0..15
    const int sl   = blockIdx.x % NSLICE;   // 0..47
    const int i0   = sl * I_TILE;
    const int b0   = bg * 8 + wv * 2;       // this wave's 2 batches

    // ---- pre-swizzled global sources for global_load_lds (v4-proven) ----
    // LDS byte q = (wv*4+t)*1024 + lane*16 (linear dest). Inverse swizzle:
    // row rr=q>>8, cb=(q&255)^((rr&15)<<4); js=rr&31; c=(rr>>5)*64+cb/4.
    const float* wsrc[4];
    #pragma unroll
    for (int t = 0; t < 4; ++t) {
        const int q  = (wv * 4 + t) * 1024 + lane * 16;
        const int rr = q >> 8;
        const int cb = (q & 255) ^ ((rr & 15) << 4);
        const int js = rr & 31;
        const int c  = (rr >> 5) * 64 + (cb >> 2);
        wsrc[t] = W + (size_t)js * WJ + c;
    }

    auto stage = [&](int buf, int i) {
        #pragma unroll
        for (int t = 0; t < 4; ++t)
            __builtin_amdgcn_global_load_lds(
                (const __attribute__((address_space(1))) uint32_t*)
                    (wsrc[t] + (size_t)i * 128),
                (__attribute__((address_space(3))) uint32_t*)
                    &Wt[buf][(wv * 4 + t) * 256],
                16, 0, 0);
    };

    stage(0, i0);

    // ---- x slice -> LDS (384 float4s, coalesced) ----
    for (int cf = tid; cf < 384; cf += 256) {
        const int bl = cf / 48;
        const int rm = cf - bl * 48;
        float4 v = *reinterpret_cast<const float4*>(
            x + ((size_t)(bg * 8 + bl) * I_CAPS + i0) * 8 + rm * 4);
        *reinterpret_cast<float4*>(xs + bl * 192 + rm * 4) = v;
    }

    // Vacc fragment, prescaled to log2 domain
    float Vr[2][8];
    if (R > 0) {
        #pragma unroll
        for (int bb = 0; bb < 2; ++bb) {
            const float* vp =
                Vacc + ((size_t)(b0 + bb) * J_CAPS + j) * K_DIM + kh * 8;
            const float4 va = *reinterpret_cast<const float4*>(vp);
            const float4 vb = *reinterpret_cast<const float4*>(vp + 4);
            Vr[bb][0] = va.x * 1.44269504f; Vr[bb][1] = va.y * 1.44269504f;
            Vr[bb][2] = va.z * 1.44269504f; Vr[bb][3] = va.w * 1.44269504f;
            Vr[bb][4] = vb.x * 1.44269504f; Vr[bb][5] = vb.y * 1.44269504f;
            Vr[bb][6] = vb.z * 1.44269504f; Vr[bb][7] = vb.w * 1.44269504f;
        }
    }

    float sacc[2][8];
    #pragma unroll
    for (int bb = 0; bb < 2; ++bb)
        #pragma unroll
        for (int kk = 0; kk < 8; ++kk) sacc[bb][kk] = 0.0f;

    __syncthreads();   // drains vmcnt: first W tile + xs ready

    const int sw = (j & 15) << 4;    // read-side swizzle (row = lane)

    for (int ii = 0; ii < I_TILE; ++ii) {
        const int cur = ii & 1;
        if (ii + 1 < I_TILE) stage(cur ^ 1, i0 + ii + 1);

        // x fragments: wave-uniform LDS address -> broadcast, conflict-free
        float4 xa[2], xb[2];
        #pragma unroll
        for (int bb = 0; bb < 2; ++bb) {
            const float* xp = xs + (wv * 2 + bb) * 192 + ii * 8;
            xa[bb] = *reinterpret_cast<const float4*>(xp);
            xb[bb] = *reinterpret_cast<const float4*>(xp + 4);
        }

        const char* lbase =
            reinterpret_cast<const char*>(&Wt[cur][0]) + lane * 256;

        float u[2][8];
        #pragma unroll
        for (int kk = 0; kk < 8; ++kk) {
            const float4 w0 = *reinterpret_cast<const float4*>(
                lbase + ((kk * 32) ^ sw));
            const float4 w1 = *reinterpret_cast<const float4*>(
                lbase + ((kk * 32 + 16) ^ sw));
            #pragma unroll
            for (int bb = 0; bb < 2; ++bb) {
                float acc;
                acc = w0.x * xa[bb].x;
                acc = fmaf(w0.y, xa[bb].y, acc);
                acc = fmaf(w0.z, xa[bb].z, acc);
                acc = fmaf(w0.w, xa[bb].w, acc);
                acc = fmaf(w1.x, xb[bb].x, acc);
                acc = fmaf(w1.y, xb[bb].y, acc);
                acc = fmaf(w1.z, xb[bb].z, acc);
                acc = fmaf(w1.w, xb[bb].w, acc);
                u[bb][kk] = acc;
            }
        }

        if (R == 0) {
            #pragma unroll
            for (int bb = 0; bb < 2; ++bb)
                #pragma unroll
                for (int kk = 0; kk < 8; ++kk)
                    sacc[bb][kk] = fmaf(0.03125f, u[bb][kk], sacc[bb][kk]);
        } else {
            // logits (log2 domain), full-k via one cross-half shuffle each
            float p0 = u[0][0] * Vr[0][0];
            float p1 = u[1][0] * Vr[1][0];
            #pragma unroll
            for (int kk = 1; kk < 8; ++kk) {
                p0 = fmaf(u[0][kk], Vr[0][kk], p0);
                p1 = fmaf(u[1][kk], Vr[1][kk], p1);
            }
            p0 += __shfl_xor(p0, 32);
            p1 += __shfl_xor(p1, 32);
            // paired softmax: kh=0 half handles batch 0, kh=1 half batch 1
            const float pq = kh ? p1 : p0;
            const float e  = exp2f(pq);          // no max-subtract: |pq| small
            float den = e;
            den += __shfl_xor(den, 1);
            den += __shfl_xor(den, 2);
            den += __shfl_xor(den, 4);
            den += __shfl_xor(den, 8);
            den += __shfl_xor(den, 16);
            const float cf_own = e * __builtin_amdgcn_rcpf(den);
            const float cf_oth = __shfl_xor(cf_own, 32);
            const float cf0 = kh ? cf_oth : cf_own;
            const float cf1 = kh ? cf_own : cf_oth;
            #pragma unroll
            for (int kk = 0; kk < 8; ++kk) {
                sacc[0][kk] = fmaf(cf0, u[0][kk], sacc[0][kk]);
                sacc[1][kk] = fmaf(cf1, u[1][kk], sacc[1][kk]);
            }
        }
        __syncthreads();   // prefetch landed (vmcnt0) + reads of cur done
    }

    // ---- epilogue: per-wave LDS transpose -> COALESCED atomics ----
    // Wt is dead (final barrier above). Each wave uses a private 4KB region,
    // so no further barrier needed. Store swizzle k' = k ^ ((j>>1)&15):
    // writes and reads both spread across banks (2-way max = free).
    {
        float* ep = &Wt[0][0] + wv * 1024;
        #pragma unroll
        for (int bb = 0; bb < 2; ++bb)
            #pragma unroll
            for (int kk = 0; kk < 8; ++kk)
                ep[bb * 512 + j * 16 + ((kh * 8 + kk) ^ ((j >> 1) & 15))] =
                    sacc[bb][kk];

        float* sg = s + (size_t)b0 * 512;   // flat (b0..b0+1, j, k)
        #pragma unroll
        for (int c = 0; c < 16; ++c) {
            const int m   = c * 64 + lane;      // flat (bb, j, k)
            const int bb2 = m >> 9;
            const int j2  = (m >> 4) & 31;
            const int k2  = m & 15;
            const float v = ep[bb2 * 512 + j2 * 16 + (k2 ^ ((j2 >> 1) & 15))];
            atomicAdd(&sg[m], v);               // 64 contiguous addrs/instr
        }
    }
}

// MODE 0: Vacc = v, zero s;  MODE 1: Vacc += v, zero s;  MODE 2: out = v
template<int MODE>
__global__ __launch_bounds__(256)
void caps_squash(float* __restrict__ s,
                 float* __restrict__ Vacc,
                 float* __restrict__ out)
{
    const int t = blockIdx.x * 256 + threadIdx.x;   // (b,j,k), k fastest
    const float sv = s[t];
    float p = sv * sv;
    p += __shfl_xor(p, 1);
    p += __shfl_xor(p, 2);
    p += __shfl_xor(p, 4);
    p += __shfl_xor(p, 8);
    const float scale = p / ((1.0f + p) * sqrtf(p + 1e-7f));
    const float v = scale * sv;
    if (MODE == 0)      { Vacc[t] = v;  s[t] = 0.0f; }
    else if (MODE == 1) { Vacc[t] += v; s[t] = 0.0f; }
    else                { out[t] = v; }
}

extern "C" void kernel_launch(void* const* d_in, const int* in_sizes, int n_in,
                              void* d_out, int out_size, void* d_ws, size_t ws_size,
                              hipStream_t stream)
{
    const float* x = (const float*)d_in[0];   // [128,1152,8]
    const float* W = (const float*)d_in[1];   // [32,1152,16,8]
    float* out  = (float*)d_out;              // [128,32,16]
    float* Vacc = (float*)d_ws;               // 65536 floats
    float* s    = Vacc + 65536;               // 65536 floats

    hipMemsetAsync(s, 0, (size_t)65536 * sizeof(float), stream);

    dim3 grid(16 * NSLICE);   // 768 WGs = 3/CU
    dim3 blk(256);

    caps_route<0><<<grid, blk, 0, stream>>>(x, W, Vacc, s);
    caps_squash<0><<<256, 256, 0, stream>>>(s, Vacc, out);

    caps_route<1><<<grid, blk, 0, stream>>>(x, W, Vacc, s);
    caps_squash<1><<<256, 256, 0, stream>>>(s, Vacc, out);

    caps_route<2><<<grid, blk, 0, stream>>>(x, W, Vacc, s);
    caps_squash<2><<<256, 256, 0, stream>>>(s, Vacc, out);
}